// Round 16
// baseline (458.598 us; speedup 1.0000x reference)
//
#include <hip/hip_runtime.h>
#include <hip/hip_bf16.h>

// GCN: 6 conv layers (2->32->64->64x4), segment-max pool to 512 graphs, FC head.
// Dtypes DETECTED at runtime. CSR via dst-bucket binning (r6). Gather-first
// layers, ONE WAVE PER NODE (r9), bf16 activations (r12), packed dual-edge
// row loads (r15: 66->58.6us). r15 lesson: TWO dependent round-trips per batch
// (idx load -> row load). This round: adjacency preloaded into REGISTERS
// (one coalesced load, idx via __shfl = no memory latency), 16 row-loads in
// flight, bf16-packed W matvec (halved LDS traffic).

#define N_NODES 50000
#define N_GRAPHS 512
#define WIDTH 64
#define NBUCK 196                 // ceil(50000/256) dst buckets of 256 nodes
#define BINBLK 256                // edge-chunk blocks for hist/bin passes

// weight offsets (floats) inside the converted-weights block
#define OFF_W1   0
#define OFF_B1   64
#define OFF_W2   96
#define OFF_B2   2144
#define OFF_CW   2208
#define OFF_CB   18592
#define OFF_FW1  18848
#define OFF_FB1  22944
#define OFF_FW2  23008
#define OFF_FB2  25056
#define OFF_FW3  25088
#define OFF_FB3  25152
#define TOTAL_W  25154
#define TOTAL_X  100000
#define TOTAL_CVT (TOTAL_X + TOTAL_W)

__device__ __forceinline__ float elu_f(float x) {
    return x > 0.f ? x : expm1f(x);
}

__device__ __forceinline__ unsigned fmono(float v) {
    unsigned b = __float_as_uint(v);
    return (b & 0x80000000u) ? ~b : (b | 0x80000000u);
}
__device__ __forceinline__ float funmono(unsigned m) {
    unsigned b = (m & 0x80000000u) ? (m ^ 0x80000000u) : ~m;
    return __uint_as_float(b);
}

// bf16x2 packed decode (exact: bf16->f32 is a 16-bit shift)
__device__ __forceinline__ float blo(unsigned u) { return __uint_as_float(u << 16); }
__device__ __forceinline__ float bhi(unsigned u) { return __uint_as_float(u & 0xFFFF0000u); }

__device__ __forceinline__ unsigned packbf2(float lo, float hi) {
    __hip_bfloat16 l = __float2bfloat16(lo);
    __hip_bfloat16 h = __float2bfloat16(hi);
    return (unsigned)*(unsigned short*)&l | ((unsigned)*(unsigned short*)&h << 16);
}

// ---- dtype detection: flags[0]=ints-are-int64, flags[1]=floats-are-bf16 ----
__global__ void detect_kernel(const void* __restrict__ eidx,
                              const void* __restrict__ x,
                              int* __restrict__ flags) {
    const int* e32 = (const int*)eidx;
    int i64 = ((e32[1] | e32[3] | e32[5] | e32[7]) == 0) ? 1 : 0;
    const unsigned short* h = (const unsigned short*)x;
    int cnt = 0;
    for (int i = 0; i < 32; ++i) {
        unsigned b = (h[2 * i] >> 8) & 0x7F;
        if (b >= 0x3C && b <= 0x42) cnt++;
    }
    flags[0] = i64;
    flags[1] = (cnt >= 16) ? 1 : 0;
}

// ---- convert x + all weight tensors to one contiguous f32 block ----
struct CvtArgs {
    const void* src[13];
    int off[13];
    int total;
};

__global__ void cvt_all_kernel(CvtArgs a, float* __restrict__ out,
                               const int* __restrict__ flags) {
    const int bf = flags[1];
    for (int idx = blockIdx.x * blockDim.x + threadIdx.x; idx < a.total;
         idx += gridDim.x * blockDim.x) {
        int t = 0;
        for (int k = 1; k < 13; ++k) if (idx >= a.off[k]) t = k;
        int i = idx - a.off[t];
        float v = bf ? __bfloat162float(((const __hip_bfloat16*)a.src[t])[i])
                     : ((const float*)a.src[t])[i];
        out[idx] = v;
    }
}

__global__ void cvt_batch_kernel(const void* __restrict__ in, int* __restrict__ out,
                                 int n, const int* __restrict__ flags) {
    int i = blockIdx.x * blockDim.x + threadIdx.x;
    if (i >= n) return;
    out[i] = flags[0] ? (int)((const long long*)in)[i] : ((const int*)in)[i];
}

__device__ __forceinline__ int eidx_read(const void* eidx, long long i, int is64) {
    return is64 ? (int)((const long long*)eidx)[i] : ((const int*)eidx)[i];
}

// ---- pass A: per-block dst-bucket histogram -> gtable[b*BINBLK + blk] ----
__global__ __launch_bounds__(256) void histA_kernel(const void* __restrict__ eidx, int E,
                                                    int* __restrict__ gtable,
                                                    const int* __restrict__ flags) {
    __shared__ int hist[NBUCK];
    const int t = threadIdx.x, blk = blockIdx.x;
    if (t < NBUCK) hist[t] = 0;
    __syncthreads();
    const int chunk = (E + BINBLK - 1) / BINBLK;
    const int e0 = blk * chunk, e1 = min(E, e0 + chunk);
    const int is64 = flags[0];
    for (int e = e0 + t; e < e1; e += 256) {
        int d = eidx_read(eidx, (long long)E + e, is64);
        atomicAdd(&hist[d >> 8], 1);
    }
    __syncthreads();
    if (t < NBUCK) gtable[t * BINBLK + blk] = hist[t];
}

// ---- generic hierarchical exclusive scan (n <= 256*256) ----
__global__ void scan_a_kernel(const int* __restrict__ in, int* __restrict__ out,
                              int* __restrict__ bsum, int n) {
    __shared__ int s[256];
    int i = blockIdx.x * 256 + threadIdx.x;
    int v = (i < n) ? in[i] : 0;
    s[threadIdx.x] = v;
    __syncthreads();
    for (int o = 1; o < 256; o <<= 1) {
        int t = (threadIdx.x >= o) ? s[threadIdx.x - o] : 0;
        __syncthreads();
        s[threadIdx.x] += t;
        __syncthreads();
    }
    if (i < n) out[i] = s[threadIdx.x] - v;
    if (threadIdx.x == 255) bsum[blockIdx.x] = s[255];
}

__global__ void scan_b_kernel(int* __restrict__ bsum, int NB) {
    __shared__ int s[256];
    int v = (threadIdx.x < NB) ? bsum[threadIdx.x] : 0;
    s[threadIdx.x] = v;
    __syncthreads();
    for (int o = 1; o < 256; o <<= 1) {
        int t = (threadIdx.x >= o) ? s[threadIdx.x - o] : 0;
        __syncthreads();
        s[threadIdx.x] += t;
        __syncthreads();
    }
    if (threadIdx.x < NB) bsum[threadIdx.x] = s[threadIdx.x] - v;
}

__global__ void scan_c_kernel(int* __restrict__ arr, const int* __restrict__ bsum, int n) {
    int i = blockIdx.x * 256 + threadIdx.x;
    if (i < n) arr[i] += bsum[i >> 8];
}

// ---- pass C: bin edges into bucket-contiguous (s | d<<16) pairs ----
__global__ __launch_bounds__(256) void binC_kernel(const void* __restrict__ eidx, int E,
                                                   const int* __restrict__ gscan,
                                                   unsigned* __restrict__ binned,
                                                   const int* __restrict__ flags) {
    __shared__ int cur[NBUCK];
    const int t = threadIdx.x, blk = blockIdx.x;
    if (t < NBUCK) cur[t] = gscan[t * BINBLK + blk];
    __syncthreads();
    const int chunk = (E + BINBLK - 1) / BINBLK;
    const int e0 = blk * chunk, e1 = min(E, e0 + chunk);
    const int is64 = flags[0];
    for (int e = e0 + t; e < e1; e += 256) {
        int s = eidx_read(eidx, e, is64);
        int d = eidx_read(eidx, (long long)E + e, is64);
        int pos = atomicAdd(&cur[d >> 8], 1);
        binned[pos] = (unsigned)s | ((unsigned)d << 16);
    }
}

// ---- pass D: per-bucket counts -> rowPtr/dinv, then local-cursor CSR fill ----
__global__ __launch_bounds__(256) void binD_kernel(const int* __restrict__ gscan,
                                                   const unsigned* __restrict__ binned,
                                                   int* __restrict__ rowPtr,
                                                   float* __restrict__ dinv,
                                                   unsigned short* __restrict__ csr_src,
                                                   int N, int E) {
    __shared__ int cnt[256];
    __shared__ int scn[256];
    __shared__ int cur[256];
    const int b = blockIdx.x, t = threadIdx.x;
    const int base = b << 8;
    const int start = gscan[b * BINBLK];
    const int end = (b == NBUCK - 1) ? E : gscan[(b + 1) * BINBLK];
    cnt[t] = 0;
    __syncthreads();
    for (int i = start + t; i < end; i += 256)
        atomicAdd(&cnt[(binned[i] >> 16) - base], 1);
    __syncthreads();
    int c = cnt[t];
    scn[t] = c;
    __syncthreads();
    for (int o = 1; o < 256; o <<= 1) {
        int v = (t >= o) ? scn[t - o] : 0;
        __syncthreads();
        scn[t] += v;
        __syncthreads();
    }
    int excl = start + scn[t] - c;
    int node = base + t;
    if (node < N) {
        rowPtr[node] = excl;
        dinv[node] = rsqrtf((float)c + 1.0f);
    }
    if (b == NBUCK - 1 && t == 0) rowPtr[N] = E;
    cur[t] = excl;
    __syncthreads();
    for (int i = start + t; i < end; i += 256) {
        unsigned p = binned[i];
        int pos = atomicAdd(&cur[(p >> 16) - base], 1);
        csr_src[pos] = (unsigned short)(p & 0xFFFFu);
    }
}

// ---- hp0 = x * dinv (pre-scaled layer-1 input, [N,2], kept f32) ----
__global__ void scale_x_kernel(const float* __restrict__ xf,
                               const float* __restrict__ dinv,
                               float* __restrict__ hp0, int n2) {
    int i = blockIdx.x * blockDim.x + threadIdx.x;
    if (i < n2) hp0[i] = xf[i] * dinv[i >> 1];
}

// ---- L1: gather 2-wide lane-per-edge -> @W1[2,32]+b1 -> elu -> *dinv -> bf16 ----
__global__ __launch_bounds__(256) void fused2_kernel(
    const int* __restrict__ rowPtr, const unsigned short* __restrict__ csr_src,
    const float* __restrict__ hp0, const float* __restrict__ dinv,
    const float* __restrict__ W, const float* __restrict__ bias,
    __hip_bfloat16* __restrict__ hp_out, int N) {
    __shared__ float Ws[64];
    __shared__ float bs[32];
    const int t = threadIdx.x;
    if (t < 64) Ws[t] = W[t];
    if (t < 32) bs[t] = bias[t];
    __syncthreads();
    const int wave = t >> 6, lane = t & 63;
    const int node = blockIdx.x * 4 + wave;
    if (node >= N) return;
    const int r0 = rowPtr[node], r1 = rowPtr[node + 1];
    float g0 = 0.f, g1 = 0.f;
    for (int e = r0 + lane; e < r1; e += 64) {
        int s = csr_src[e];
        float2 v = *(const float2*)&hp0[2 * s];
        g0 += v.x; g1 += v.y;
    }
    for (int o = 32; o; o >>= 1) {
        g0 += __shfl_xor(g0, o, 64);
        g1 += __shfl_xor(g1, o, 64);
    }
    const float2 self = *(const float2*)&hp0[2 * node];
    const float di = dinv[node];
    g0 = (g0 + self.x) * di;
    g1 = (g1 + self.y) * di;
    if (lane < 32) {
        float o = g0 * Ws[lane] + g1 * Ws[32 + lane] + bs[lane];
        hp_out[(size_t)node * 32 + lane] = __float2bfloat16(elu_f(o) * di);
    }
}

// ---- L2: gather 32-wide bf16; quarter-wave per edge (16 lanes x 4B = row);
//      adjacency in registers (idx via shfl); 8 loads in flight = 32 edges ----
__global__ __launch_bounds__(256) void fused32_kernel(
    const int* __restrict__ rowPtr, const unsigned short* __restrict__ csr_src,
    const __hip_bfloat16* __restrict__ hp_in, const float* __restrict__ dinv,
    const float* __restrict__ W, const float* __restrict__ bias,
    __hip_bfloat16* __restrict__ hp_out, int N) {
    __shared__ unsigned Ws2[16 * 64];   // packed bf16 pairs [k2][outcol]
    __shared__ float bs[64];
    __shared__ float hs[4 * 32];
    const int t = threadIdx.x;
    for (int i = t; i < 16 * 64; i += 256) {
        int k2 = i >> 6, c = i & 63;
        Ws2[i] = packbf2(W[(2 * k2) * 64 + c], W[(2 * k2 + 1) * 64 + c]);
    }
    if (t < 64) bs[t] = bias[t];
    __syncthreads();
    const int wave = t >> 6, lane = t & 63;
    const int node = blockIdx.x * 4 + wave;
    if (node >= N) return;
    const int q = lane >> 4, fl = lane & 15;
    const int fl2 = fl << 1;
    const int r0 = rowPtr[node], r1 = rowPtr[node + 1];
    const int deg = r1 - r0;
    int myIdx = 0;
    if (lane < deg) myIdx = csr_src[r0 + lane];
    const int nreg = deg < 64 ? deg : 64;
    float a0 = 0.f, b0 = 0.f, a1 = 0.f, b1 = 0.f;
    int base = 0;
    for (; base + 31 < nreg; base += 32) {      // 8 loads in flight (4 edges each)
        unsigned u[8];
#pragma unroll
        for (int s = 0; s < 8; ++s) {
            int idx = __shfl(myIdx, base + 4 * s + q, 64);
            u[s] = *(const unsigned*)&hp_in[(size_t)idx * 32 + fl2];
        }
#pragma unroll
        for (int s = 0; s < 8; ++s) {
            if (s & 1) { a1 += blo(u[s]); b1 += bhi(u[s]); }
            else       { a0 += blo(u[s]); b0 += bhi(u[s]); }
        }
    }
    for (; base + 3 < nreg; base += 4) {
        int idx = __shfl(myIdx, base + q, 64);
        unsigned uu = *(const unsigned*)&hp_in[(size_t)idx * 32 + fl2];
        a0 += blo(uu); b0 += bhi(uu);
    }
    {
        int rem = nreg - base;                  // 0..3
        int sel = base + (q < rem ? q : 0);
        int idx = __shfl(myIdx, sel, 64);       // all lanes active
        if (q < rem) {
            unsigned uu = *(const unsigned*)&hp_in[(size_t)idx * 32 + fl2];
            a0 += blo(uu); b0 += bhi(uu);
        }
    }
    for (int ee = 64 + q; ee < deg; ee += 4) {  // rare deg>64 tail
        int idx = csr_src[r0 + ee];
        unsigned uu = *(const unsigned*)&hp_in[(size_t)idx * 32 + fl2];
        a0 += blo(uu); b0 += bhi(uu);
    }
    float a = a0 + a1, b = b0 + b1;
    a += __shfl_xor(a, 16, 64); b += __shfl_xor(b, 16, 64);
    a += __shfl_xor(a, 32, 64); b += __shfl_xor(b, 32, 64);
    const float di = dinv[node];
    if (q == 0) {
        unsigned su = *(const unsigned*)&hp_in[(size_t)node * 32 + fl2];
        float2 w;
        w.x = (a + blo(su)) * di;
        w.y = (b + bhi(su)) * di;
        *(float2*)&hs[wave * 32 + fl2] = w;
    }
    float o = 0.f;
#pragma unroll
    for (int k2 = 0; k2 < 16; ++k2) {
        float2 h2 = *(const float2*)&hs[wave * 32 + (k2 << 1)];
        unsigned wp = Ws2[k2 * 64 + lane];
        o += h2.x * blo(wp) + h2.y * bhi(wp);
    }
    o += bs[lane];
    hp_out[(size_t)node * 64 + lane] = __float2bfloat16(elu_f(o) * di);
}

// ---- 64->64 layer: half-wave per edge (32 lanes x 4B = row); adjacency in
//      registers (idx via shfl); 16 loads in flight = 32 edges; bf16-packed W
//      matvec. Optionally fused pool. ----
template<int LAST>
__global__ __launch_bounds__(256) void fused64_kernel(
    const int* __restrict__ rowPtr, const unsigned short* __restrict__ csr_src,
    const __hip_bfloat16* __restrict__ hp_in, const float* __restrict__ dinv,
    const float* __restrict__ W, const float* __restrict__ bias,
    __hip_bfloat16* __restrict__ hp_out, unsigned* __restrict__ pooled,
    const int* __restrict__ batch, int N) {
    __shared__ unsigned Ws2[32 * 64];   // packed bf16 pairs [k2][outcol], 8KB
    __shared__ float bs[64];
    __shared__ float hs[4 * 64];
    const int t = threadIdx.x;
    for (int i = t; i < 32 * 64; i += 256) {
        int k2 = i >> 6, c = i & 63;
        Ws2[i] = packbf2(W[(2 * k2) * 64 + c], W[(2 * k2 + 1) * 64 + c]);
    }
    if (t < 64) bs[t] = bias[t];
    __syncthreads();
    const int wave = t >> 6, lane = t & 63;
    const int node = blockIdx.x * 4 + wave;
    if (node >= N) return;
    const int half = lane >> 5, fl = lane & 31;
    const int fl2 = fl << 1;
    const int r0 = rowPtr[node], r1 = rowPtr[node + 1];
    const int deg = r1 - r0;
    int myIdx = 0;
    if (lane < deg) myIdx = csr_src[r0 + lane];
    const int nreg = deg < 64 ? deg : 64;
    float a0 = 0.f, b0 = 0.f, a1 = 0.f, b1 = 0.f;
    float a2 = 0.f, b2 = 0.f, a3 = 0.f, b3 = 0.f;
    int base = 0;
    for (; base + 31 < nreg; base += 32) {      // 16 loads in flight (2 edges each)
        unsigned u[16];
#pragma unroll
        for (int s = 0; s < 16; ++s) {
            int idx = __shfl(myIdx, base + 2 * s + half, 64);
            u[s] = *(const unsigned*)&hp_in[(size_t)idx * 64 + fl2];
        }
#pragma unroll
        for (int s = 0; s < 16; ++s) {
            switch (s & 3) {
                case 0: a0 += blo(u[s]); b0 += bhi(u[s]); break;
                case 1: a1 += blo(u[s]); b1 += bhi(u[s]); break;
                case 2: a2 += blo(u[s]); b2 += bhi(u[s]); break;
                default: a3 += blo(u[s]); b3 += bhi(u[s]); break;
            }
        }
    }
    for (; base + 1 < nreg; base += 2) {
        int idx = __shfl(myIdx, base + half, 64);
        unsigned uu = *(const unsigned*)&hp_in[(size_t)idx * 64 + fl2];
        a0 += blo(uu); b0 += bhi(uu);
    }
    {
        int idxL = __shfl(myIdx, nreg > 0 ? nreg - 1 : 0, 64);  // all lanes active
        if (base < nreg && half == 0) {
            unsigned uu = *(const unsigned*)&hp_in[(size_t)idxL * 64 + fl2];
            a0 += blo(uu); b0 += bhi(uu);
        }
    }
    for (int ee = 64 + half; ee < deg; ee += 2) {  // rare deg>64 tail
        int idx = csr_src[r0 + ee];
        unsigned uu = *(const unsigned*)&hp_in[(size_t)idx * 64 + fl2];
        a0 += blo(uu); b0 += bhi(uu);
    }
    float a = (a0 + a1) + (a2 + a3);
    float b = (b0 + b1) + (b2 + b3);
    a += __shfl_xor(a, 32, 64);
    b += __shfl_xor(b, 32, 64);
    const float di = dinv[node];
    if (half == 0) {
        unsigned su = *(const unsigned*)&hp_in[(size_t)node * 64 + fl2];  // self-loop
        float2 w;
        w.x = (a + blo(su)) * di;
        w.y = (b + bhi(su)) * di;
        *(float2*)&hs[wave * 64 + fl2] = w;
    }
    float o = 0.f;
#pragma unroll
    for (int k2 = 0; k2 < 32; ++k2) {
        float2 h2 = *(const float2*)&hs[wave * 64 + (k2 << 1)];
        unsigned wp = Ws2[k2 * 64 + lane];
        o += h2.x * blo(wp) + h2.y * bhi(wp);
    }
    o += bs[lane];
    float v = elu_f(o);
    if (LAST) {
        atomicMax(&pooled[batch[node] * 64 + lane], fmono(v));
    } else {
        hp_out[(size_t)node * 64 + lane] = __float2bfloat16(v * di);
    }
}

// ---- FC head: one block (64 threads) per graph ----
__global__ void fc_kernel(const unsigned* __restrict__ pooled,
                          const float* __restrict__ Wall,
                          void* __restrict__ out,
                          const int* __restrict__ flags) {
    __shared__ float g[64], y1[64], y2[32], z[2];
    const int bid = blockIdx.x, t = threadIdx.x;
    g[t] = funmono(pooled[bid * 64 + t]);
    __syncthreads();
    {
        float acc = Wall[OFF_FB1 + t];
        for (int k = 0; k < 64; ++k) acc += g[k] * Wall[OFF_FW1 + k * 64 + t];
        y1[t] = elu_f(acc);
    }
    __syncthreads();
    if (t < 32) {
        float acc = Wall[OFF_FB2 + t];
        for (int k = 0; k < 64; ++k) acc += y1[k] * Wall[OFF_FW2 + k * 32 + t];
        y2[t] = elu_f(acc);
    }
    __syncthreads();
    if (t < 2) {
        float acc = Wall[OFF_FB3 + t];
        for (int k = 0; k < 32; ++k) acc += y2[k] * Wall[OFF_FW3 + k * 2 + t];
        z[t] = acc;
    }
    __syncthreads();
    if (t < 2) {
        float m = fmaxf(z[0], z[1]);
        float l = m + logf(expf(z[0] - m) + expf(z[1] - m));
        float r = z[t] - l;
        if (flags[1]) ((__hip_bfloat16*)out)[bid * 2 + t] = __float2bfloat16(r);
        else          ((float*)out)[bid * 2 + t] = r;
    }
}

extern "C" void kernel_launch(void* const* d_in, const int* in_sizes, int n_in,
                              void* d_out, int out_size, void* d_ws, size_t ws_size,
                              hipStream_t stream) {
    const int N = in_sizes[0] / 2;       // 50000
    const int E = in_sizes[1] / 2;       // 1600000
    const int NT = NBUCK * BINBLK;       // 50176 table entries

    const void* x    = d_in[0];
    const void* eidx = d_in[1];
    const void* batch = d_in[2];

    // workspace layout (~25 MB)
    char* ws = (char*)d_ws;
    size_t off = 0;
    auto alloc = [&](size_t bytes) { char* p = ws + off; off += (bytes + 255) & ~(size_t)255; return p; };
    int*   flags   = (int*)  alloc(2 * sizeof(int));
    float* xcvt    = (float*)alloc(TOTAL_CVT * sizeof(float));
    int*   batch32 = (int*)  alloc(N_NODES * sizeof(int));
    float* dinv    = (float*)alloc(N_NODES * sizeof(float));
    int*   rowPtr  = (int*)  alloc((N_NODES + 1) * sizeof(int));
    int*   gtable  = (int*)  alloc(NT * sizeof(int));            // 200 KB
    int*   gscan   = (int*)  alloc(NT * sizeof(int));            // 200 KB
    int*   gbsum   = (int*)  alloc(256 * sizeof(int));
    unsigned* pooled = (unsigned*)alloc(N_GRAPHS * WIDTH * sizeof(unsigned));
    unsigned* binned = (unsigned*)alloc((size_t)E * sizeof(unsigned));      // 6.4 MB
    unsigned short* csr16 = (unsigned short*)alloc((size_t)E * sizeof(unsigned short)); // 3.2 MB
    float* hp0     = (float*)alloc((size_t)N_NODES * 2 * sizeof(float));
    __hip_bfloat16* hpA = (__hip_bfloat16*)alloc((size_t)N_NODES * 64 * sizeof(__hip_bfloat16)); // 6.4 MB
    __hip_bfloat16* hpB = (__hip_bfloat16*)alloc((size_t)N_NODES * 64 * sizeof(__hip_bfloat16)); // 6.4 MB

    float* xf   = xcvt;
    float* Wall = xcvt + TOTAL_X;

    detect_kernel<<<1, 1, 0, stream>>>(eidx, x, flags);

    CvtArgs ca;
    ca.src[0] = x;        ca.off[0] = 0;
    ca.src[1] = d_in[3];  ca.off[1] = TOTAL_X + OFF_W1;
    ca.src[2] = d_in[4];  ca.off[2] = TOTAL_X + OFF_B1;
    ca.src[3] = d_in[5];  ca.off[3] = TOTAL_X + OFF_W2;
    ca.src[4] = d_in[6];  ca.off[4] = TOTAL_X + OFF_B2;
    ca.src[5] = d_in[7];  ca.off[5] = TOTAL_X + OFF_CW;
    ca.src[6] = d_in[8];  ca.off[6] = TOTAL_X + OFF_CB;
    ca.src[7] = d_in[9];  ca.off[7] = TOTAL_X + OFF_FW1;
    ca.src[8] = d_in[10]; ca.off[8] = TOTAL_X + OFF_FB1;
    ca.src[9] = d_in[11]; ca.off[9] = TOTAL_X + OFF_FW2;
    ca.src[10] = d_in[12]; ca.off[10] = TOTAL_X + OFF_FB2;
    ca.src[11] = d_in[13]; ca.off[11] = TOTAL_X + OFF_FW3;
    ca.src[12] = d_in[14]; ca.off[12] = TOTAL_X + OFF_FB3;
    ca.total = TOTAL_CVT;
    cvt_all_kernel<<<(TOTAL_CVT + 255) / 256, 256, 0, stream>>>(ca, xcvt, flags);
    cvt_batch_kernel<<<(N + 255) / 256, 256, 0, stream>>>(batch, batch32, N, flags);

    hipMemsetAsync(pooled, 0, N_GRAPHS * WIDTH * sizeof(unsigned), stream);

    // CSR build via dst-bucket binning
    histA_kernel<<<BINBLK, 256, 0, stream>>>(eidx, E, gtable, flags);
    scan_a_kernel<<<(NT + 255) / 256, 256, 0, stream>>>(gtable, gscan, gbsum, NT);
    scan_b_kernel<<<1, 256, 0, stream>>>(gbsum, (NT + 255) / 256);
    scan_c_kernel<<<(NT + 255) / 256, 256, 0, stream>>>(gscan, gbsum, NT);
    binC_kernel<<<BINBLK, 256, 0, stream>>>(eidx, E, gscan, binned, flags);
    binD_kernel<<<NBUCK, 256, 0, stream>>>(gscan, binned, rowPtr, dinv, csr16, N, E);

    scale_x_kernel<<<(2 * N + 255) / 256, 256, 0, stream>>>(xf, dinv, hp0, 2 * N);

    const int FG = (N + 3) / 4;   // one wave per node
    fused2_kernel<<<FG, 256, 0, stream>>>(rowPtr, csr16, hp0, dinv,
        Wall + OFF_W1, Wall + OFF_B1, hpA, N);
    fused32_kernel<<<FG, 256, 0, stream>>>(rowPtr, csr16, hpA, dinv,
        Wall + OFF_W2, Wall + OFF_B2, hpB, N);
    fused64_kernel<0><<<FG, 256, 0, stream>>>(rowPtr, csr16, hpB, dinv,
        Wall + OFF_CW + 0 * 4096, Wall + OFF_CB + 0 * 64, hpA, nullptr, nullptr, N);
    fused64_kernel<0><<<FG, 256, 0, stream>>>(rowPtr, csr16, hpA, dinv,
        Wall + OFF_CW + 1 * 4096, Wall + OFF_CB + 1 * 64, hpB, nullptr, nullptr, N);
    fused64_kernel<0><<<FG, 256, 0, stream>>>(rowPtr, csr16, hpB, dinv,
        Wall + OFF_CW + 2 * 4096, Wall + OFF_CB + 2 * 64, hpA, nullptr, nullptr, N);
    fused64_kernel<1><<<FG, 256, 0, stream>>>(rowPtr, csr16, hpA, dinv,
        Wall + OFF_CW + 3 * 4096, Wall + OFF_CB + 3 * 64, nullptr, pooled, batch32, N);

    fc_kernel<<<N_GRAPHS, 64, 0, stream>>>(pooled, Wall, d_out, flags);
}

// Round 17
// 416.610 us; speedup vs baseline: 1.1008x; 1.1008x over previous
//
#include <hip/hip_runtime.h>
#include <hip/hip_bf16.h>

// GCN: 6 conv layers (2->32->64->64x4), segment-max pool to 512 graphs, FC head.
// Dtypes DETECTED at runtime. CSR via dst-bucket binning (r6). Gather-first
// layers, ONE WAVE PER NODE (r9), bf16 activations (r12), packed dual-edge
// row loads (r15: 66->58.6us = best). r16 lesson: shfl-adjacency regressed
// (VALU 40->55%); idx loads were L1-hits, gather is bound by per-CU L2-txn
// throughput (~10cyc/txn), floor = 2 txns/edge. [Exact revert to round-15.]

#define N_NODES 50000
#define N_GRAPHS 512
#define WIDTH 64
#define NBUCK 196                 // ceil(50000/256) dst buckets of 256 nodes
#define BINBLK 256                // edge-chunk blocks for hist/bin passes

// weight offsets (floats) inside the converted-weights block
#define OFF_W1   0
#define OFF_B1   64
#define OFF_W2   96
#define OFF_B2   2144
#define OFF_CW   2208
#define OFF_CB   18592
#define OFF_FW1  18848
#define OFF_FB1  22944
#define OFF_FW2  23008
#define OFF_FB2  25056
#define OFF_FW3  25088
#define OFF_FB3  25152
#define TOTAL_W  25154
#define TOTAL_X  100000
#define TOTAL_CVT (TOTAL_X + TOTAL_W)

__device__ __forceinline__ float elu_f(float x) {
    return x > 0.f ? x : expm1f(x);
}

__device__ __forceinline__ unsigned fmono(float v) {
    unsigned b = __float_as_uint(v);
    return (b & 0x80000000u) ? ~b : (b | 0x80000000u);
}
__device__ __forceinline__ float funmono(unsigned m) {
    unsigned b = (m & 0x80000000u) ? (m ^ 0x80000000u) : ~m;
    return __uint_as_float(b);
}

// bf16x2 packed decode (exact: bf16->f32 is a 16-bit shift)
__device__ __forceinline__ float blo(unsigned u) { return __uint_as_float(u << 16); }
__device__ __forceinline__ float bhi(unsigned u) { return __uint_as_float(u & 0xFFFF0000u); }

// ---- dtype detection: flags[0]=ints-are-int64, flags[1]=floats-are-bf16 ----
__global__ void detect_kernel(const void* __restrict__ eidx,
                              const void* __restrict__ x,
                              int* __restrict__ flags) {
    const int* e32 = (const int*)eidx;
    int i64 = ((e32[1] | e32[3] | e32[5] | e32[7]) == 0) ? 1 : 0;
    const unsigned short* h = (const unsigned short*)x;
    int cnt = 0;
    for (int i = 0; i < 32; ++i) {
        unsigned b = (h[2 * i] >> 8) & 0x7F;
        if (b >= 0x3C && b <= 0x42) cnt++;
    }
    flags[0] = i64;
    flags[1] = (cnt >= 16) ? 1 : 0;
}

// ---- convert x + all weight tensors to one contiguous f32 block ----
struct CvtArgs {
    const void* src[13];
    int off[13];
    int total;
};

__global__ void cvt_all_kernel(CvtArgs a, float* __restrict__ out,
                               const int* __restrict__ flags) {
    const int bf = flags[1];
    for (int idx = blockIdx.x * blockDim.x + threadIdx.x; idx < a.total;
         idx += gridDim.x * blockDim.x) {
        int t = 0;
        for (int k = 1; k < 13; ++k) if (idx >= a.off[k]) t = k;
        int i = idx - a.off[t];
        float v = bf ? __bfloat162float(((const __hip_bfloat16*)a.src[t])[i])
                     : ((const float*)a.src[t])[i];
        out[idx] = v;
    }
}

__global__ void cvt_batch_kernel(const void* __restrict__ in, int* __restrict__ out,
                                 int n, const int* __restrict__ flags) {
    int i = blockIdx.x * blockDim.x + threadIdx.x;
    if (i >= n) return;
    out[i] = flags[0] ? (int)((const long long*)in)[i] : ((const int*)in)[i];
}

__device__ __forceinline__ int eidx_read(const void* eidx, long long i, int is64) {
    return is64 ? (int)((const long long*)eidx)[i] : ((const int*)eidx)[i];
}

// ---- pass A: per-block dst-bucket histogram -> gtable[b*BINBLK + blk] ----
__global__ __launch_bounds__(256) void histA_kernel(const void* __restrict__ eidx, int E,
                                                    int* __restrict__ gtable,
                                                    const int* __restrict__ flags) {
    __shared__ int hist[NBUCK];
    const int t = threadIdx.x, blk = blockIdx.x;
    if (t < NBUCK) hist[t] = 0;
    __syncthreads();
    const int chunk = (E + BINBLK - 1) / BINBLK;
    const int e0 = blk * chunk, e1 = min(E, e0 + chunk);
    const int is64 = flags[0];
    for (int e = e0 + t; e < e1; e += 256) {
        int d = eidx_read(eidx, (long long)E + e, is64);
        atomicAdd(&hist[d >> 8], 1);
    }
    __syncthreads();
    if (t < NBUCK) gtable[t * BINBLK + blk] = hist[t];
}

// ---- generic hierarchical exclusive scan (n <= 256*256) ----
__global__ void scan_a_kernel(const int* __restrict__ in, int* __restrict__ out,
                              int* __restrict__ bsum, int n) {
    __shared__ int s[256];
    int i = blockIdx.x * 256 + threadIdx.x;
    int v = (i < n) ? in[i] : 0;
    s[threadIdx.x] = v;
    __syncthreads();
    for (int o = 1; o < 256; o <<= 1) {
        int t = (threadIdx.x >= o) ? s[threadIdx.x - o] : 0;
        __syncthreads();
        s[threadIdx.x] += t;
        __syncthreads();
    }
    if (i < n) out[i] = s[threadIdx.x] - v;
    if (threadIdx.x == 255) bsum[blockIdx.x] = s[255];
}

__global__ void scan_b_kernel(int* __restrict__ bsum, int NB) {
    __shared__ int s[256];
    int v = (threadIdx.x < NB) ? bsum[threadIdx.x] : 0;
    s[threadIdx.x] = v;
    __syncthreads();
    for (int o = 1; o < 256; o <<= 1) {
        int t = (threadIdx.x >= o) ? s[threadIdx.x - o] : 0;
        __syncthreads();
        s[threadIdx.x] += t;
        __syncthreads();
    }
    if (threadIdx.x < NB) bsum[threadIdx.x] = s[threadIdx.x] - v;
}

__global__ void scan_c_kernel(int* __restrict__ arr, const int* __restrict__ bsum, int n) {
    int i = blockIdx.x * 256 + threadIdx.x;
    if (i < n) arr[i] += bsum[i >> 8];
}

// ---- pass C: bin edges into bucket-contiguous (s | d<<16) pairs ----
__global__ __launch_bounds__(256) void binC_kernel(const void* __restrict__ eidx, int E,
                                                   const int* __restrict__ gscan,
                                                   unsigned* __restrict__ binned,
                                                   const int* __restrict__ flags) {
    __shared__ int cur[NBUCK];
    const int t = threadIdx.x, blk = blockIdx.x;
    if (t < NBUCK) cur[t] = gscan[t * BINBLK + blk];
    __syncthreads();
    const int chunk = (E + BINBLK - 1) / BINBLK;
    const int e0 = blk * chunk, e1 = min(E, e0 + chunk);
    const int is64 = flags[0];
    for (int e = e0 + t; e < e1; e += 256) {
        int s = eidx_read(eidx, e, is64);
        int d = eidx_read(eidx, (long long)E + e, is64);
        int pos = atomicAdd(&cur[d >> 8], 1);
        binned[pos] = (unsigned)s | ((unsigned)d << 16);
    }
}

// ---- pass D: per-bucket counts -> rowPtr/dinv, then local-cursor CSR fill ----
__global__ __launch_bounds__(256) void binD_kernel(const int* __restrict__ gscan,
                                                   const unsigned* __restrict__ binned,
                                                   int* __restrict__ rowPtr,
                                                   float* __restrict__ dinv,
                                                   unsigned short* __restrict__ csr_src,
                                                   int N, int E) {
    __shared__ int cnt[256];
    __shared__ int scn[256];
    __shared__ int cur[256];
    const int b = blockIdx.x, t = threadIdx.x;
    const int base = b << 8;
    const int start = gscan[b * BINBLK];
    const int end = (b == NBUCK - 1) ? E : gscan[(b + 1) * BINBLK];
    cnt[t] = 0;
    __syncthreads();
    for (int i = start + t; i < end; i += 256)
        atomicAdd(&cnt[(binned[i] >> 16) - base], 1);
    __syncthreads();
    int c = cnt[t];
    scn[t] = c;
    __syncthreads();
    for (int o = 1; o < 256; o <<= 1) {
        int v = (t >= o) ? scn[t - o] : 0;
        __syncthreads();
        scn[t] += v;
        __syncthreads();
    }
    int excl = start + scn[t] - c;
    int node = base + t;
    if (node < N) {
        rowPtr[node] = excl;
        dinv[node] = rsqrtf((float)c + 1.0f);
    }
    if (b == NBUCK - 1 && t == 0) rowPtr[N] = E;
    cur[t] = excl;
    __syncthreads();
    for (int i = start + t; i < end; i += 256) {
        unsigned p = binned[i];
        int pos = atomicAdd(&cur[(p >> 16) - base], 1);
        csr_src[pos] = (unsigned short)(p & 0xFFFFu);
    }
}

// ---- hp0 = x * dinv (pre-scaled layer-1 input, [N,2], kept f32) ----
__global__ void scale_x_kernel(const float* __restrict__ xf,
                               const float* __restrict__ dinv,
                               float* __restrict__ hp0, int n2) {
    int i = blockIdx.x * blockDim.x + threadIdx.x;
    if (i < n2) hp0[i] = xf[i] * dinv[i >> 1];
}

// ---- L1: gather 2-wide lane-per-edge -> @W1[2,32]+b1 -> elu -> *dinv -> bf16 ----
__global__ __launch_bounds__(256) void fused2_kernel(
    const int* __restrict__ rowPtr, const unsigned short* __restrict__ csr_src,
    const float* __restrict__ hp0, const float* __restrict__ dinv,
    const float* __restrict__ W, const float* __restrict__ bias,
    __hip_bfloat16* __restrict__ hp_out, int N) {
    __shared__ float Ws[64];
    __shared__ float bs[32];
    const int t = threadIdx.x;
    if (t < 64) Ws[t] = W[t];
    if (t < 32) bs[t] = bias[t];
    __syncthreads();
    const int wave = t >> 6, lane = t & 63;
    const int node = blockIdx.x * 4 + wave;
    if (node >= N) return;
    const int r0 = rowPtr[node], r1 = rowPtr[node + 1];
    float g0 = 0.f, g1 = 0.f;
    for (int e = r0 + lane; e < r1; e += 64) {
        int s = csr_src[e];
        float2 v = *(const float2*)&hp0[2 * s];
        g0 += v.x; g1 += v.y;
    }
    for (int o = 32; o; o >>= 1) {
        g0 += __shfl_xor(g0, o, 64);
        g1 += __shfl_xor(g1, o, 64);
    }
    const float2 self = *(const float2*)&hp0[2 * node];
    const float di = dinv[node];
    g0 = (g0 + self.x) * di;
    g1 = (g1 + self.y) * di;
    if (lane < 32) {
        float o = g0 * Ws[lane] + g1 * Ws[32 + lane] + bs[lane];
        hp_out[(size_t)node * 32 + lane] = __float2bfloat16(elu_f(o) * di);
    }
}

// ---- L2: gather 32-wide bf16, quarter-wave per edge (16 lanes x 4B = row),
//      4 edges per load instruction, 8 loads in flight (32 edges) ----
__global__ __launch_bounds__(256) void fused32_kernel(
    const int* __restrict__ rowPtr, const unsigned short* __restrict__ csr_src,
    const __hip_bfloat16* __restrict__ hp_in, const float* __restrict__ dinv,
    const float* __restrict__ W, const float* __restrict__ bias,
    __hip_bfloat16* __restrict__ hp_out, int N) {
    __shared__ float Ws[32 * 64];
    __shared__ float bs[64];
    __shared__ float hs[4 * 32];
    const int t = threadIdx.x;
    for (int i = t; i < 32 * 64; i += 256) Ws[i] = W[i];
    if (t < 64) bs[t] = bias[t];
    __syncthreads();
    const int wave = t >> 6, lane = t & 63;
    const int node = blockIdx.x * 4 + wave;
    if (node >= N) return;
    const int q = lane >> 4, fl = lane & 15;   // quarter-wave, feature pair index
    const int fl2 = fl << 1;
    const int r0 = rowPtr[node], r1 = rowPtr[node + 1];
    float a0 = 0.f, b0 = 0.f, a1 = 0.f, b1 = 0.f;
    int e = r0 + q;                            // this quarter owns edges r0+q, +4, ...
    for (; e + 28 < r1; e += 32) {             // 8 loads in flight = 32 edges
        unsigned u0 = *(const unsigned*)&hp_in[(size_t)csr_src[e]      * 32 + fl2];
        unsigned u1 = *(const unsigned*)&hp_in[(size_t)csr_src[e + 4]  * 32 + fl2];
        unsigned u2 = *(const unsigned*)&hp_in[(size_t)csr_src[e + 8]  * 32 + fl2];
        unsigned u3 = *(const unsigned*)&hp_in[(size_t)csr_src[e + 12] * 32 + fl2];
        unsigned u4 = *(const unsigned*)&hp_in[(size_t)csr_src[e + 16] * 32 + fl2];
        unsigned u5 = *(const unsigned*)&hp_in[(size_t)csr_src[e + 20] * 32 + fl2];
        unsigned u6 = *(const unsigned*)&hp_in[(size_t)csr_src[e + 24] * 32 + fl2];
        unsigned u7 = *(const unsigned*)&hp_in[(size_t)csr_src[e + 28] * 32 + fl2];
        a0 += blo(u0); b0 += bhi(u0);
        a1 += blo(u1); b1 += bhi(u1);
        a0 += blo(u2); b0 += bhi(u2);
        a1 += blo(u3); b1 += bhi(u3);
        a0 += blo(u4); b0 += bhi(u4);
        a1 += blo(u5); b1 += bhi(u5);
        a0 += blo(u6); b0 += bhi(u6);
        a1 += blo(u7); b1 += bhi(u7);
    }
    for (; e < r1; e += 4) {
        unsigned u = *(const unsigned*)&hp_in[(size_t)csr_src[e] * 32 + fl2];
        a0 += blo(u); b0 += bhi(u);
    }
    float a = a0 + a1, b = b0 + b1;
    a += __shfl_xor(a, 16, 64); b += __shfl_xor(b, 16, 64);
    a += __shfl_xor(a, 32, 64); b += __shfl_xor(b, 32, 64);
    const float di = dinv[node];
    if (q == 0) {
        unsigned su = *(const unsigned*)&hp_in[(size_t)node * 32 + fl2];
        float2 w;
        w.x = (a + blo(su)) * di;
        w.y = (b + bhi(su)) * di;
        *(float2*)&hs[wave * 32 + fl2] = w;
    }
    float o = 0.f;
#pragma unroll
    for (int k = 0; k < 32; ++k) o += hs[wave * 32 + k] * Ws[k * 64 + lane];
    o += bs[lane];
    hp_out[(size_t)node * 64 + lane] = __float2bfloat16(elu_f(o) * di);
}

// ---- 64->64 layer: half-wave per edge (32 lanes x 4B = row), 2 edges per load
//      instruction, 8 loads in flight (16 edges). Optionally fused pool. ----
template<int LAST>
__global__ __launch_bounds__(256) void fused64_kernel(
    const int* __restrict__ rowPtr, const unsigned short* __restrict__ csr_src,
    const __hip_bfloat16* __restrict__ hp_in, const float* __restrict__ dinv,
    const float* __restrict__ W, const float* __restrict__ bias,
    __hip_bfloat16* __restrict__ hp_out, unsigned* __restrict__ pooled,
    const int* __restrict__ batch, int N) {
    __shared__ float Ws[64 * 64];
    __shared__ float bs[64];
    __shared__ float hs[4 * 64];
    const int t = threadIdx.x;
    {
        const float4* W4 = (const float4*)W;
        float4* Ws4 = (float4*)Ws;
        for (int i = t; i < 1024; i += 256) Ws4[i] = W4[i];
    }
    if (t < 64) bs[t] = bias[t];
    __syncthreads();
    const int wave = t >> 6, lane = t & 63;
    const int node = blockIdx.x * 4 + wave;
    if (node >= N) return;
    const int half = lane >> 5, fl = lane & 31;  // half-wave, feature pair index
    const int fl2 = fl << 1;
    const int r0 = rowPtr[node], r1 = rowPtr[node + 1];
    float a0 = 0.f, b0 = 0.f, a1 = 0.f, b1 = 0.f, a2 = 0.f, b2 = 0.f, a3 = 0.f, b3 = 0.f;
    int e = r0 + half;                           // this half owns edges r0+half, +2, ...
    for (; e + 14 < r1; e += 16) {               // 8 loads in flight = 16 edges
        unsigned u0 = *(const unsigned*)&hp_in[(size_t)csr_src[e]      * 64 + fl2];
        unsigned u1 = *(const unsigned*)&hp_in[(size_t)csr_src[e + 2]  * 64 + fl2];
        unsigned u2 = *(const unsigned*)&hp_in[(size_t)csr_src[e + 4]  * 64 + fl2];
        unsigned u3 = *(const unsigned*)&hp_in[(size_t)csr_src[e + 6]  * 64 + fl2];
        unsigned u4 = *(const unsigned*)&hp_in[(size_t)csr_src[e + 8]  * 64 + fl2];
        unsigned u5 = *(const unsigned*)&hp_in[(size_t)csr_src[e + 10] * 64 + fl2];
        unsigned u6 = *(const unsigned*)&hp_in[(size_t)csr_src[e + 12] * 64 + fl2];
        unsigned u7 = *(const unsigned*)&hp_in[(size_t)csr_src[e + 14] * 64 + fl2];
        a0 += blo(u0); b0 += bhi(u0);
        a1 += blo(u1); b1 += bhi(u1);
        a2 += blo(u2); b2 += bhi(u2);
        a3 += blo(u3); b3 += bhi(u3);
        a0 += blo(u4); b0 += bhi(u4);
        a1 += blo(u5); b1 += bhi(u5);
        a2 += blo(u6); b2 += bhi(u6);
        a3 += blo(u7); b3 += bhi(u7);
    }
    for (; e < r1; e += 2) {
        unsigned u = *(const unsigned*)&hp_in[(size_t)csr_src[e] * 64 + fl2];
        a0 += blo(u); b0 += bhi(u);
    }
    float a = (a0 + a1) + (a2 + a3);
    float b = (b0 + b1) + (b2 + b3);
    a += __shfl_xor(a, 32, 64);
    b += __shfl_xor(b, 32, 64);
    const float di = dinv[node];
    if (half == 0) {
        unsigned su = *(const unsigned*)&hp_in[(size_t)node * 64 + fl2];  // self-loop
        float2 w;
        w.x = (a + blo(su)) * di;
        w.y = (b + bhi(su)) * di;
        *(float2*)&hs[wave * 64 + fl2] = w;
    }
    float o = 0.f;
#pragma unroll
    for (int k = 0; k < 64; ++k) o += hs[wave * 64 + k] * Ws[k * 64 + lane];
    o += bs[lane];
    float v = elu_f(o);
    if (LAST) {
        atomicMax(&pooled[batch[node] * 64 + lane], fmono(v));
    } else {
        hp_out[(size_t)node * 64 + lane] = __float2bfloat16(v * di);
    }
}

// ---- FC head: one block (64 threads) per graph ----
__global__ void fc_kernel(const unsigned* __restrict__ pooled,
                          const float* __restrict__ Wall,
                          void* __restrict__ out,
                          const int* __restrict__ flags) {
    __shared__ float g[64], y1[64], y2[32], z[2];
    const int bid = blockIdx.x, t = threadIdx.x;
    g[t] = funmono(pooled[bid * 64 + t]);
    __syncthreads();
    {
        float acc = Wall[OFF_FB1 + t];
        for (int k = 0; k < 64; ++k) acc += g[k] * Wall[OFF_FW1 + k * 64 + t];
        y1[t] = elu_f(acc);
    }
    __syncthreads();
    if (t < 32) {
        float acc = Wall[OFF_FB2 + t];
        for (int k = 0; k < 64; ++k) acc += y1[k] * Wall[OFF_FW2 + k * 32 + t];
        y2[t] = elu_f(acc);
    }
    __syncthreads();
    if (t < 2) {
        float acc = Wall[OFF_FB3 + t];
        for (int k = 0; k < 32; ++k) acc += y2[k] * Wall[OFF_FW3 + k * 2 + t];
        z[t] = acc;
    }
    __syncthreads();
    if (t < 2) {
        float m = fmaxf(z[0], z[1]);
        float l = m + logf(expf(z[0] - m) + expf(z[1] - m));
        float r = z[t] - l;
        if (flags[1]) ((__hip_bfloat16*)out)[bid * 2 + t] = __float2bfloat16(r);
        else          ((float*)out)[bid * 2 + t] = r;
    }
}

extern "C" void kernel_launch(void* const* d_in, const int* in_sizes, int n_in,
                              void* d_out, int out_size, void* d_ws, size_t ws_size,
                              hipStream_t stream) {
    const int N = in_sizes[0] / 2;       // 50000
    const int E = in_sizes[1] / 2;       // 1600000
    const int NT = NBUCK * BINBLK;       // 50176 table entries

    const void* x    = d_in[0];
    const void* eidx = d_in[1];
    const void* batch = d_in[2];

    // workspace layout (~25 MB)
    char* ws = (char*)d_ws;
    size_t off = 0;
    auto alloc = [&](size_t bytes) { char* p = ws + off; off += (bytes + 255) & ~(size_t)255; return p; };
    int*   flags   = (int*)  alloc(2 * sizeof(int));
    float* xcvt    = (float*)alloc(TOTAL_CVT * sizeof(float));
    int*   batch32 = (int*)  alloc(N_NODES * sizeof(int));
    float* dinv    = (float*)alloc(N_NODES * sizeof(float));
    int*   rowPtr  = (int*)  alloc((N_NODES + 1) * sizeof(int));
    int*   gtable  = (int*)  alloc(NT * sizeof(int));            // 200 KB
    int*   gscan   = (int*)  alloc(NT * sizeof(int));            // 200 KB
    int*   gbsum   = (int*)  alloc(256 * sizeof(int));
    unsigned* pooled = (unsigned*)alloc(N_GRAPHS * WIDTH * sizeof(unsigned));
    unsigned* binned = (unsigned*)alloc((size_t)E * sizeof(unsigned));      // 6.4 MB
    unsigned short* csr16 = (unsigned short*)alloc((size_t)E * sizeof(unsigned short)); // 3.2 MB
    float* hp0     = (float*)alloc((size_t)N_NODES * 2 * sizeof(float));
    __hip_bfloat16* hpA = (__hip_bfloat16*)alloc((size_t)N_NODES * 64 * sizeof(__hip_bfloat16)); // 6.4 MB
    __hip_bfloat16* hpB = (__hip_bfloat16*)alloc((size_t)N_NODES * 64 * sizeof(__hip_bfloat16)); // 6.4 MB

    float* xf   = xcvt;
    float* Wall = xcvt + TOTAL_X;

    detect_kernel<<<1, 1, 0, stream>>>(eidx, x, flags);

    CvtArgs ca;
    ca.src[0] = x;        ca.off[0] = 0;
    ca.src[1] = d_in[3];  ca.off[1] = TOTAL_X + OFF_W1;
    ca.src[2] = d_in[4];  ca.off[2] = TOTAL_X + OFF_B1;
    ca.src[3] = d_in[5];  ca.off[3] = TOTAL_X + OFF_W2;
    ca.src[4] = d_in[6];  ca.off[4] = TOTAL_X + OFF_B2;
    ca.src[5] = d_in[7];  ca.off[5] = TOTAL_X + OFF_CW;
    ca.src[6] = d_in[8];  ca.off[6] = TOTAL_X + OFF_CB;
    ca.src[7] = d_in[9];  ca.off[7] = TOTAL_X + OFF_FW1;
    ca.src[8] = d_in[10]; ca.off[8] = TOTAL_X + OFF_FB1;
    ca.src[9] = d_in[11]; ca.off[9] = TOTAL_X + OFF_FW2;
    ca.src[10] = d_in[12]; ca.off[10] = TOTAL_X + OFF_FB2;
    ca.src[11] = d_in[13]; ca.off[11] = TOTAL_X + OFF_FW3;
    ca.src[12] = d_in[14]; ca.off[12] = TOTAL_X + OFF_FB3;
    ca.total = TOTAL_CVT;
    cvt_all_kernel<<<(TOTAL_CVT + 255) / 256, 256, 0, stream>>>(ca, xcvt, flags);
    cvt_batch_kernel<<<(N + 255) / 256, 256, 0, stream>>>(batch, batch32, N, flags);

    hipMemsetAsync(pooled, 0, N_GRAPHS * WIDTH * sizeof(unsigned), stream);

    // CSR build via dst-bucket binning
    histA_kernel<<<BINBLK, 256, 0, stream>>>(eidx, E, gtable, flags);
    scan_a_kernel<<<(NT + 255) / 256, 256, 0, stream>>>(gtable, gscan, gbsum, NT);
    scan_b_kernel<<<1, 256, 0, stream>>>(gbsum, (NT + 255) / 256);
    scan_c_kernel<<<(NT + 255) / 256, 256, 0, stream>>>(gscan, gbsum, NT);
    binC_kernel<<<BINBLK, 256, 0, stream>>>(eidx, E, gscan, binned, flags);
    binD_kernel<<<NBUCK, 256, 0, stream>>>(gscan, binned, rowPtr, dinv, csr16, N, E);

    scale_x_kernel<<<(2 * N + 255) / 256, 256, 0, stream>>>(xf, dinv, hp0, 2 * N);

    const int FG = (N + 3) / 4;   // one wave per node
    fused2_kernel<<<FG, 256, 0, stream>>>(rowPtr, csr16, hp0, dinv,
        Wall + OFF_W1, Wall + OFF_B1, hpA, N);
    fused32_kernel<<<FG, 256, 0, stream>>>(rowPtr, csr16, hpA, dinv,
        Wall + OFF_W2, Wall + OFF_B2, hpB, N);
    fused64_kernel<0><<<FG, 256, 0, stream>>>(rowPtr, csr16, hpB, dinv,
        Wall + OFF_CW + 0 * 4096, Wall + OFF_CB + 0 * 64, hpA, nullptr, nullptr, N);
    fused64_kernel<0><<<FG, 256, 0, stream>>>(rowPtr, csr16, hpA, dinv,
        Wall + OFF_CW + 1 * 4096, Wall + OFF_CB + 1 * 64, hpB, nullptr, nullptr, N);
    fused64_kernel<0><<<FG, 256, 0, stream>>>(rowPtr, csr16, hpB, dinv,
        Wall + OFF_CW + 2 * 4096, Wall + OFF_CB + 2 * 64, hpA, nullptr, nullptr, N);
    fused64_kernel<1><<<FG, 256, 0, stream>>>(rowPtr, csr16, hpA, dinv,
        Wall + OFF_CW + 3 * 4096, Wall + OFF_CB + 3 * 64, nullptr, pooled, batch32, N);

    fc_kernel<<<N_GRAPHS, 64, 0, stream>>>(pooled, Wall, d_out, flags);
}